// Round 7
// baseline (179.203 us; speedup 1.0000x reference)
//
#include <hip/hip_runtime.h>
#include <hip/hip_bf16.h>

#define D 128

typedef __attribute__((ext_vector_type(8))) short short8v;  // 8 bf16 (4 VGPRs)
typedef __attribute__((ext_vector_type(4))) float f32x4;

__device__ __forceinline__ short f2bf(float f) {
    union { float f; unsigned u; } v;
    v.f = f;
    unsigned u = v.u;
    unsigned r = (u + 0x7FFFu + ((u >> 16) & 1u)) >> 16;  // RNE
    return (short)r;
}

// pack two f32 -> one dword of 2 bf16 (compiler emits v_cvt_pk_bf16_f32)
__device__ __forceinline__ unsigned pkbf2(float lo, float hi) {
    __hip_bfloat162 h = __float22bfloat162_rn(make_float2(lo, hi));
    union { __hip_bfloat162 h; unsigned u; } v;
    v.h = h;
    return v.u;
}

// ---------------- prep: role-split — hist(dst) + pack WT2 ----------------
// WT2[nn][k], nn in [0,128) output col, k in [0,256): k<128 -> Ws[k][nn], else Wn[k-128][nn].
__global__ __launch_bounds__(256) void prep_kernel(const int* __restrict__ dst,
                                                   int* __restrict__ counts, int nE,
                                                   const float* __restrict__ Ws,
                                                   const float* __restrict__ Wn,
                                                   short* __restrict__ WT2) {
    const int nbE = (nE + 255) >> 8;
    const int b = blockIdx.x;
    if (b < nbE) {
        int e = b * 256 + threadIdx.x;
        if (e < nE) atomicAdd(&counts[dst[e]], 1);
    } else {
        int idx = (b - nbE) * 256 + threadIdx.x;  // < 128*256 = 32768
        int nn = idx >> 8;
        int k = idx & 255;
        float v = (k < D) ? Ws[k * D + nn] : Wn[(k - D) * D + nn];
        WT2[idx] = f2bf(v);
    }
}

// ---------------- scan A: per-block (1024-chunk) totals ----------------
__global__ __launch_bounds__(256) void scan_partial_kernel(const int* __restrict__ counts,
                                                           int* __restrict__ bsums, int n) {
    __shared__ int wsum[4];
    const int t = threadIdx.x;
    const int i0 = blockIdx.x * 1024 + t * 4;
    int s = 0;
#pragma unroll
    for (int j = 0; j < 4; ++j) s += (i0 + j < n) ? counts[i0 + j] : 0;
#pragma unroll
    for (int off = 32; off > 0; off >>= 1) s += __shfl_down(s, off, 64);
    if ((t & 63) == 0) wsum[t >> 6] = s;
    __syncthreads();
    if (t == 0) bsums[blockIdx.x] = wsum[0] + wsum[1] + wsum[2] + wsum[3];
}

// ---------------- scan B: exclusive scan of block sums (nb <= 128) ----------------
__global__ __launch_bounds__(128) void scan_bsums_kernel(const int* __restrict__ bsums,
                                                         int* __restrict__ ebsums,
                                                         int* __restrict__ rowptr_n,
                                                         int nb) {
    __shared__ int sh[128];
    const int t = threadIdx.x;
    int v = (t < nb) ? bsums[t] : 0;
    sh[t] = v;
    __syncthreads();
    for (int off = 1; off < 128; off <<= 1) {
        int u = (t >= off) ? sh[t - off] : 0;
        __syncthreads();
        sh[t] += u;
        __syncthreads();
    }
    if (t < nb) ebsums[t] = sh[t] - v;  // exclusive
    if (t == 127) *rowptr_n = sh[127];  // grand total -> rowptr[n]
}

// ---------------- scan C: chunk exclusive scan + cursor init ----------------
__global__ __launch_bounds__(256) void scan_final_kernel(int* __restrict__ counts,
                                                         const int* __restrict__ ebsums,
                                                         int* __restrict__ rowptr, int n) {
    __shared__ int sh[256];
    const int t = threadIdx.x;
    const int i0 = blockIdx.x * 1024 + t * 4;
    int c[4];
    int s = 0;
#pragma unroll
    for (int j = 0; j < 4; ++j) {
        c[j] = (i0 + j < n) ? counts[i0 + j] : 0;
        s += c[j];
    }
    sh[t] = s;
    __syncthreads();
    for (int off = 1; off < 256; off <<= 1) {
        int u = (t >= off) ? sh[t - off] : 0;
        __syncthreads();
        sh[t] += u;
        __syncthreads();
    }
    int run = ebsums[blockIdx.x] + sh[t] - s;
#pragma unroll
    for (int j = 0; j < 4; ++j) {
        int i = i0 + j;
        if (i < n) {
            rowptr[i] = run;
            counts[i] = run;  // cursor init
            run += c[j];
        }
    }
}

// ---------------- CSR fill: csr[pos] = src, pos = cursor[dst]++ ----------------
__global__ __launch_bounds__(256) void fill_kernel(const int* __restrict__ src,
                                                   const int* __restrict__ dst,
                                                   int* __restrict__ cursor,
                                                   int* __restrict__ csr, int nE) {
    int e = blockIdx.x * 256 + threadIdx.x;
    if (e < nE) {
        int pos = atomicAdd(&cursor[dst[e]], 1);
        csr[pos] = src[e];
    }
}

// ---------------- gather: aggb[d] = bf16( (1/deg) * sum_{e in csr[d]} x[src_e] ) ----------
// One wave per node; lane handles channels {2*lane, 2*lane+1} (float2 per edge, coalesced).
__global__ __launch_bounds__(256) void gather_kernel(const int* __restrict__ rowptr,
                                                     const int* __restrict__ csr,
                                                     const float* __restrict__ x,
                                                     unsigned short* __restrict__ aggb,
                                                     int n) {
    const int wave = threadIdx.x >> 6;
    const int lane = threadIdx.x & 63;
    const int d = blockIdx.x * 4 + wave;
    if (d >= n) return;  // no barriers

    const int beg = rowptr[d];
    const int end = rowptr[d + 1];
    float ax = 0.f, ay = 0.f;

    int i = beg;
    for (; i + 3 < end; i += 4) {
        int s0 = csr[i], s1 = csr[i + 1], s2 = csr[i + 2], s3 = csr[i + 3];
        float2 v0 = *reinterpret_cast<const float2*>(x + (size_t)s0 * D + lane * 2);
        float2 v1 = *reinterpret_cast<const float2*>(x + (size_t)s1 * D + lane * 2);
        float2 v2 = *reinterpret_cast<const float2*>(x + (size_t)s2 * D + lane * 2);
        float2 v3 = *reinterpret_cast<const float2*>(x + (size_t)s3 * D + lane * 2);
        ax += (v0.x + v1.x) + (v2.x + v3.x);
        ay += (v0.y + v1.y) + (v2.y + v3.y);
    }
    for (; i < end; ++i) {
        int s0 = csr[i];
        float2 v0 = *reinterpret_cast<const float2*>(x + (size_t)s0 * D + lane * 2);
        ax += v0.x;
        ay += v0.y;
    }

    const float inv = 1.0f / fmaxf((float)(end - beg), 1.0f);
    *reinterpret_cast<unsigned*>(aggb + (size_t)d * D + lane * 2) = pkbf2(ax * inv, ay * inv);
}

// ---------------- fused GEMM K=256: out = relu([x|agg] @ WT2^T + bs + bn) ----------------
// Persistent; 4 waves/block; wave owns 2 col-tiles (32 cols), B-frags (2x8 short8v = 64 VGPR)
// resident for whole kernel. Grid-strides over 16-row strips with double-buffered A prefetch.
// A: k<128 from f32 x (cvt_pk on fly), k>=128 from bf16 agg. C/D: col=lane&15,
// row=(lane>>4)*4+reg [m89]. Single final write: out f32, relu'd.
__global__ __launch_bounds__(256) void gemm_fused_kernel(const float* __restrict__ x,
                                                         const short* __restrict__ WT2,
                                                         const float* __restrict__ bs,
                                                         const float* __restrict__ bn,
                                                         const unsigned short* __restrict__ aggb,
                                                         float* __restrict__ out,
                                                         int n, int nStrips) {
    const int wave = threadIdx.x >> 6;
    const int lane = threadIdx.x & 63;
    const int lrow = lane & 15;
    const int ko = (lane >> 4) * 8;

    short8v b[2][8];
#pragma unroll
    for (int j = 0; j < 2; ++j) {
        const short* __restrict__ wp = WT2 + (size_t)((wave * 2 + j) * 16 + lrow) * 256 + ko;
#pragma unroll
        for (int ks = 0; ks < 8; ++ks)
            b[j][ks] = *reinterpret_cast<const short8v*>(wp + ks * 32);
    }
    float bias[2];
#pragma unroll
    for (int j = 0; j < 2; ++j) {
        int c = (wave * 2 + j) * 16 + lrow;
        bias[j] = bs[c] + bn[c];
    }

    const int stride = gridDim.x;

    auto loadA = [&](int strip, float4* fx, short8v* ag) {
        const size_t row = (size_t)min(strip * 16 + lrow, n - 1);
        const float* __restrict__ xr = x + row * D + ko;
        const unsigned short* __restrict__ ar = aggb + row * D + ko;
#pragma unroll
        for (int ks = 0; ks < 4; ++ks) {
            fx[2 * ks] = *reinterpret_cast<const float4*>(xr + ks * 32);
            fx[2 * ks + 1] = *reinterpret_cast<const float4*>(xr + ks * 32 + 4);
            ag[ks] = *reinterpret_cast<const short8v*>(ar + ks * 32);
        }
    };

    auto compute = [&](int strip, const float4* fx, const short8v* ag) {
        short8v a[8];
#pragma unroll
        for (int ks = 0; ks < 4; ++ks) {
            const float4 lo = fx[2 * ks], hi = fx[2 * ks + 1];
            union { short8v s8; unsigned u[4]; } af;
            af.u[0] = pkbf2(lo.x, lo.y);
            af.u[1] = pkbf2(lo.z, lo.w);
            af.u[2] = pkbf2(hi.x, hi.y);
            af.u[3] = pkbf2(hi.z, hi.w);
            a[ks] = af.s8;
            a[ks + 4] = ag[ks];
        }
        f32x4 acc[2];
        acc[0] = (f32x4){0.f, 0.f, 0.f, 0.f};
        acc[1] = (f32x4){0.f, 0.f, 0.f, 0.f};
#pragma unroll
        for (int j = 0; j < 2; ++j)
#pragma unroll
            for (int ks = 0; ks < 8; ++ks)
                acc[j] = __builtin_amdgcn_mfma_f32_16x16x32_bf16(a[ks], b[j][ks], acc[j], 0, 0, 0);

        const int r0 = strip * 16 + (lane >> 4) * 4;
#pragma unroll
        for (int j = 0; j < 2; ++j) {
            const int c = (wave * 2 + j) * 16 + lrow;
#pragma unroll
            for (int rg = 0; rg < 4; ++rg) {
                int r = r0 + rg;
                if (r < n) out[(size_t)r * D + c] = fmaxf(acc[j][rg] + bias[j], 0.f);
            }
        }
    };

    float4 fxA[8], fxB[8];
    short8v agA[4], agB[4];
    int strip = blockIdx.x;
    if (strip >= nStrips) return;
    loadA(strip, fxA, agA);
    for (; strip < nStrips; strip += 2 * stride) {
        const int s1 = strip + stride;
        if (s1 < nStrips) loadA(s1, fxB, agB);
        compute(strip, fxA, agA);
        if (s1 < nStrips) {
            const int s2 = s1 + stride;
            if (s2 < nStrips) loadA(s2, fxA, agA);
            compute(s1, fxB, agB);
        }
    }
}

extern "C" void kernel_launch(void* const* d_in, const int* in_sizes, int n_in,
                              void* d_out, int out_size, void* d_ws, size_t ws_size,
                              hipStream_t stream) {
    const float* x  = (const float*)d_in[0];
    const int*   ei = (const int*)d_in[1];
    const float* Ws = (const float*)d_in[2];
    const float* bs = (const float*)d_in[3];
    const float* Wn = (const float*)d_in[4];
    const float* bn = (const float*)d_in[5];
    float* out = (float*)d_out;

    const int n  = in_sizes[0] / D;   // 100000
    const int nE = in_sizes[1] / 2;   // 640000
    const int* src = ei;
    const int* dst = ei + nE;
    const int nb = (n + 1023) / 1024; // 98

    // workspace layout (~29 MB)
    unsigned short* aggb = (unsigned short*)d_ws;         // n*D bf16 (25.6 MB)
    short* WT2   = (short*)(aggb + (size_t)n * D);        // 128*256 bf16 (64 KB)
    int*   counts = (int*)(WT2 + (size_t)D * 256);        // n int (becomes cursor)
    int*   rowptr = counts + n;                           // n+1 int
    int*   csr    = rowptr + n + 1;                       // nE int (2.56 MB)
    int*   bsums  = csr + nE;                             // 128 int
    int*   ebsums = bsums + 128;                          // 128 int

    const int nbE = (nE + 255) / 256;

    hipMemsetAsync(counts, 0, (size_t)n * sizeof(int), stream);
    prep_kernel<<<nbE + 128, 256, 0, stream>>>(dst, counts, nE, Ws, Wn, WT2);
    scan_partial_kernel<<<nb, 256, 0, stream>>>(counts, bsums, n);
    scan_bsums_kernel<<<1, 128, 0, stream>>>(bsums, ebsums, rowptr + n, nb);
    scan_final_kernel<<<nb, 256, 0, stream>>>(counts, ebsums, rowptr, n);
    fill_kernel<<<(nE + 255) / 256, 256, 0, stream>>>(src, dst, counts, csr, nE);

    gather_kernel<<<(n + 3) / 4, 256, 0, stream>>>(rowptr, csr, x, aggb, n);

    const int nStrips = (n + 15) / 16;  // 6250
    const int gGrid = nStrips < 1024 ? nStrips : 1024;
    gemm_fused_kernel<<<gGrid, 256, 0, stream>>>(x, WT2, bs, bn, aggb, out, n, nStrips);
}

// Round 8
// 174.415 us; speedup vs baseline: 1.0275x; 1.0275x over previous
//
#include <hip/hip_runtime.h>
#include <hip/hip_bf16.h>

#define D 128

typedef __attribute__((ext_vector_type(8))) short short8v;  // 8 bf16 (4 VGPRs)
typedef __attribute__((ext_vector_type(4))) float f32x4;

__device__ __forceinline__ short f2bf(float f) {
    union { float f; unsigned u; } v;
    v.f = f;
    unsigned u = v.u;
    unsigned r = (u + 0x7FFFu + ((u >> 16) & 1u)) >> 16;  // RNE
    return (short)r;
}

__device__ __forceinline__ float bf2f(unsigned u16) {
    union { unsigned u; float f; } v;
    v.u = u16 << 16;
    return v.f;
}

// pack two f32 -> one dword of 2 bf16 (v_cvt_pk_bf16_f32)
__device__ __forceinline__ unsigned pkbf2(float lo, float hi) {
    __hip_bfloat162 h = __float22bfloat162_rn(make_float2(lo, hi));
    union { __hip_bfloat162 h; unsigned u; } v;
    v.h = h;
    return v.u;
}

// ---------------- prep: role-split — hist(dst) | pack WT2 | pack xb ----------------
// WT2[nn][k]: nn=output col (0..127), k=0..255: k<128 -> Ws[k][nn], else Wn[k-128][nn].
// xb = bf16(x), row-major n x 128.
__global__ __launch_bounds__(256) void prep_kernel(const int* __restrict__ dst,
                                                   int* __restrict__ counts, int nE,
                                                   const float* __restrict__ Ws,
                                                   const float* __restrict__ Wn,
                                                   short* __restrict__ WT2,
                                                   const float* __restrict__ x,
                                                   unsigned short* __restrict__ xb,
                                                   int nElem) {
    const int nbE = (nE + 255) >> 8;
    const int b = blockIdx.x;
    if (b < nbE) {
        int e = b * 256 + threadIdx.x;
        if (e < nE) atomicAdd(&counts[dst[e]], 1);
    } else if (b < nbE + 128) {
        int idx = (b - nbE) * 256 + threadIdx.x;  // < 128*256 = 32768
        int nn = idx >> 8;
        int k = idx & 255;
        float v = (k < D) ? Ws[k * D + nn] : Wn[(k - D) * D + nn];
        WT2[idx] = f2bf(v);
    } else {
        int idx = (b - nbE - 128) * 256 + threadIdx.x;
        int base = idx * 8;
        if (base < nElem) {
            float4 lo = *reinterpret_cast<const float4*>(x + base);
            float4 hi = *reinterpret_cast<const float4*>(x + base + 4);
            union { short8v s8; unsigned u[4]; } p;
            p.u[0] = pkbf2(lo.x, lo.y);
            p.u[1] = pkbf2(lo.z, lo.w);
            p.u[2] = pkbf2(hi.x, hi.y);
            p.u[3] = pkbf2(hi.z, hi.w);
            *reinterpret_cast<short8v*>(xb + base) = p.s8;
        }
    }
}

// ---------------- scan A: per-block (1024-chunk) totals ----------------
__global__ __launch_bounds__(256) void scan_partial_kernel(const int* __restrict__ counts,
                                                           int* __restrict__ bsums, int n) {
    __shared__ int wsum[4];
    const int t = threadIdx.x;
    const int i0 = blockIdx.x * 1024 + t * 4;
    int s = 0;
#pragma unroll
    for (int j = 0; j < 4; ++j) s += (i0 + j < n) ? counts[i0 + j] : 0;
#pragma unroll
    for (int off = 32; off > 0; off >>= 1) s += __shfl_down(s, off, 64);
    if ((t & 63) == 0) wsum[t >> 6] = s;
    __syncthreads();
    if (t == 0) bsums[blockIdx.x] = wsum[0] + wsum[1] + wsum[2] + wsum[3];
}

// ---------------- scan B: exclusive scan of block sums (nb <= 128) ----------------
__global__ __launch_bounds__(128) void scan_bsums_kernel(const int* __restrict__ bsums,
                                                         int* __restrict__ ebsums,
                                                         int* __restrict__ rowptr_n,
                                                         int nb) {
    __shared__ int sh[128];
    const int t = threadIdx.x;
    int v = (t < nb) ? bsums[t] : 0;
    sh[t] = v;
    __syncthreads();
    for (int off = 1; off < 128; off <<= 1) {
        int u = (t >= off) ? sh[t - off] : 0;
        __syncthreads();
        sh[t] += u;
        __syncthreads();
    }
    if (t < nb) ebsums[t] = sh[t] - v;  // exclusive
    if (t == 127) *rowptr_n = sh[127];  // grand total -> rowptr[n]
}

// ---------------- scan C: chunk exclusive scan + cursor init ----------------
__global__ __launch_bounds__(256) void scan_final_kernel(int* __restrict__ counts,
                                                         const int* __restrict__ ebsums,
                                                         int* __restrict__ rowptr, int n) {
    __shared__ int sh[256];
    const int t = threadIdx.x;
    const int i0 = blockIdx.x * 1024 + t * 4;
    int c[4];
    int s = 0;
#pragma unroll
    for (int j = 0; j < 4; ++j) {
        c[j] = (i0 + j < n) ? counts[i0 + j] : 0;
        s += c[j];
    }
    sh[t] = s;
    __syncthreads();
    for (int off = 1; off < 256; off <<= 1) {
        int u = (t >= off) ? sh[t - off] : 0;
        __syncthreads();
        sh[t] += u;
        __syncthreads();
    }
    int run = ebsums[blockIdx.x] + sh[t] - s;
#pragma unroll
    for (int j = 0; j < 4; ++j) {
        int i = i0 + j;
        if (i < n) {
            rowptr[i] = run;
            counts[i] = run;  // cursor init
            run += c[j];
        }
    }
}

// ---------------- CSR fill: csr[pos] = src, pos = cursor[dst]++ ----------------
__global__ __launch_bounds__(256) void fill_kernel(const int* __restrict__ src,
                                                   const int* __restrict__ dst,
                                                   int* __restrict__ cursor,
                                                   int* __restrict__ csr, int nE) {
    int e = blockIdx.x * 256 + threadIdx.x;
    if (e < nE) {
        int pos = atomicAdd(&cursor[dst[e]], 1);
        csr[pos] = src[e];
    }
}

// ---------------- fused gather + GEMM K=256 ----------------
// Persistent, 4 waves/block, grid-stride over 16-row strips (n % 16 == 0).
// Phase G: wave w gathers mean of xb[src] for rows m0+w*4..+3 into LDS agg tile
//   (bf16x2 dwords, row stride 68 dwords to spread banks).
// Phase M: A-frag = xb rows (global, bf16 direct) + agg rows (LDS uint4);
//   B-frags (WT2) register-resident; out = relu(acc + bs + bn), written once.
// C/D: col=lane&15, row=(lane>>4)*4+reg [m89].
__global__ __launch_bounds__(256) void fused_gemm_kernel(const unsigned short* __restrict__ xb,
                                                         const short* __restrict__ WT2,
                                                         const float* __restrict__ bs,
                                                         const float* __restrict__ bn,
                                                         const int* __restrict__ rowptr,
                                                         const int* __restrict__ csr,
                                                         float* __restrict__ out,
                                                         int n, int nStrips) {
    __shared__ __align__(16) unsigned aggLds[16][68];

    const int wave = threadIdx.x >> 6;
    const int lane = threadIdx.x & 63;
    const int lrow = lane & 15;
    const int q = lane >> 4;
    const int ko = q * 8;

    // B fragments: 2 col-tiles x 8 K-steps, register-resident
    short8v b[2][8];
#pragma unroll
    for (int j = 0; j < 2; ++j) {
        const short* __restrict__ wp = WT2 + (size_t)((wave * 2 + j) * 16 + lrow) * 256 + ko;
#pragma unroll
        for (int ks = 0; ks < 8; ++ks)
            b[j][ks] = *reinterpret_cast<const short8v*>(wp + ks * 32);
    }
    float bias[2];
#pragma unroll
    for (int j = 0; j < 2; ++j) {
        int c = (wave * 2 + j) * 16 + lrow;
        bias[j] = bs[c] + bn[c];
    }

    for (int strip = blockIdx.x; strip < nStrips; strip += gridDim.x) {
        const int m0 = strip * 16;

        // ---- phase G: gather 4 rows per wave into LDS ----
#pragma unroll
        for (int j = 0; j < 4; ++j) {
            const int d = m0 + wave * 4 + j;
            const int beg = rowptr[d];
            const int end = rowptr[d + 1];
            float ax = 0.f, ay = 0.f;
            int i = beg;
            for (; i + 3 < end; i += 4) {
                int s0 = csr[i], s1 = csr[i + 1], s2 = csr[i + 2], s3 = csr[i + 3];
                unsigned v0 = *reinterpret_cast<const unsigned*>(xb + (size_t)s0 * D + lane * 2);
                unsigned v1 = *reinterpret_cast<const unsigned*>(xb + (size_t)s1 * D + lane * 2);
                unsigned v2 = *reinterpret_cast<const unsigned*>(xb + (size_t)s2 * D + lane * 2);
                unsigned v3 = *reinterpret_cast<const unsigned*>(xb + (size_t)s3 * D + lane * 2);
                ax += (bf2f(v0 & 0xffffu) + bf2f(v1 & 0xffffu)) +
                      (bf2f(v2 & 0xffffu) + bf2f(v3 & 0xffffu));
                ay += (bf2f(v0 >> 16) + bf2f(v1 >> 16)) + (bf2f(v2 >> 16) + bf2f(v3 >> 16));
            }
            for (; i < end; ++i) {
                unsigned v0 = *reinterpret_cast<const unsigned*>(xb + (size_t)csr[i] * D + lane * 2);
                ax += bf2f(v0 & 0xffffu);
                ay += bf2f(v0 >> 16);
            }
            const float inv = 1.0f / fmaxf((float)(end - beg), 1.0f);
            aggLds[wave * 4 + j][lane] = pkbf2(ax * inv, ay * inv);
        }
        __syncthreads();

        // ---- phase M: A-frags + 16 MFMA + fused epilogue ----
        short8v a[8];
        const unsigned short* __restrict__ xr = xb + (size_t)(m0 + lrow) * D + ko;
#pragma unroll
        for (int ks = 0; ks < 4; ++ks) {
            a[ks] = *reinterpret_cast<const short8v*>(xr + ks * 32);
            union { uint4 u4; short8v s8; } cv;
            cv.u4 = *reinterpret_cast<const uint4*>(&aggLds[lrow][q * 4 + ks * 16]);
            a[4 + ks] = cv.s8;
        }

        f32x4 acc[2];
        acc[0] = (f32x4){0.f, 0.f, 0.f, 0.f};
        acc[1] = (f32x4){0.f, 0.f, 0.f, 0.f};
#pragma unroll
        for (int j = 0; j < 2; ++j)
#pragma unroll
            for (int ks = 0; ks < 8; ++ks)
                acc[j] = __builtin_amdgcn_mfma_f32_16x16x32_bf16(a[ks], b[j][ks], acc[j], 0, 0, 0);

        const int r0 = m0 + q * 4;
#pragma unroll
        for (int j = 0; j < 2; ++j) {
            const int c = (wave * 2 + j) * 16 + lrow;
#pragma unroll
            for (int rg = 0; rg < 4; ++rg) {
                int r = r0 + rg;
                if (r < n) out[(size_t)r * D + c] = fmaxf(acc[j][rg] + bias[j], 0.f);
            }
        }
        __syncthreads();  // protect LDS before next strip's gather
    }
}

extern "C" void kernel_launch(void* const* d_in, const int* in_sizes, int n_in,
                              void* d_out, int out_size, void* d_ws, size_t ws_size,
                              hipStream_t stream) {
    const float* x  = (const float*)d_in[0];
    const int*   ei = (const int*)d_in[1];
    const float* Ws = (const float*)d_in[2];
    const float* bs = (const float*)d_in[3];
    const float* Wn = (const float*)d_in[4];
    const float* bn = (const float*)d_in[5];
    float* out = (float*)d_out;

    const int n  = in_sizes[0] / D;   // 100000
    const int nE = in_sizes[1] / 2;   // 640000
    const int* src = ei;
    const int* dst = ei + nE;
    const int nb = (n + 1023) / 1024; // 98
    const int nElem = n * D;

    // workspace layout (~29.1 MB)
    unsigned short* xb = (unsigned short*)d_ws;           // n*D bf16 (25.6 MB)
    short* WT2   = (short*)(xb + (size_t)nElem);          // 128*256 bf16 (64 KB)
    int*   counts = (int*)(WT2 + (size_t)D * 256);        // n int (becomes cursor)
    int*   rowptr = counts + n;                           // n+1 int
    int*   csr    = rowptr + n + 1;                       // nE int (2.56 MB)
    int*   bsums  = csr + nE;                             // 128 int
    int*   ebsums = bsums + 128;                          // 128 int

    const int nbE = (nE + 255) / 256;              // 2500
    const int nXb = (nElem / 8 + 255) / 256;       // 6250

    hipMemsetAsync(counts, 0, (size_t)n * sizeof(int), stream);
    prep_kernel<<<nbE + 128 + nXb, 256, 0, stream>>>(dst, counts, nE, Ws, Wn, WT2, x, xb, nElem);
    scan_partial_kernel<<<nb, 256, 0, stream>>>(counts, bsums, n);
    scan_bsums_kernel<<<1, 128, 0, stream>>>(bsums, ebsums, rowptr + n, nb);
    scan_final_kernel<<<nb, 256, 0, stream>>>(counts, ebsums, rowptr, n);
    fill_kernel<<<(nE + 255) / 256, 256, 0, stream>>>(src, dst, counts, csr, nE);

    const int nStrips = (n + 15) / 16;  // 6250
    const int gGrid = nStrips < 1024 ? nStrips : 1024;
    fused_gemm_kernel<<<gGrid, 256, 0, stream>>>(xb, WT2, bs, bn, rowptr, csr, out, n, nStrips);
}

// Round 9
// 170.537 us; speedup vs baseline: 1.0508x; 1.0227x over previous
//
#include <hip/hip_runtime.h>
#include <hip/hip_bf16.h>

#define D 128

typedef __attribute__((ext_vector_type(8))) short short8v;  // 8 bf16 (4 VGPRs)
typedef __attribute__((ext_vector_type(4))) float f32x4;

__device__ __forceinline__ short f2bf(float f) {
    union { float f; unsigned u; } v;
    v.f = f;
    unsigned u = v.u;
    unsigned r = (u + 0x7FFFu + ((u >> 16) & 1u)) >> 16;  // RNE
    return (short)r;
}

__device__ __forceinline__ float bf2f(unsigned u16) {
    union { unsigned u; float f; } v;
    v.u = u16 << 16;
    return v.f;
}

// pack two f32 -> one dword of 2 bf16 (v_cvt_pk_bf16_f32)
__device__ __forceinline__ unsigned pkbf2(float lo, float hi) {
    __hip_bfloat162 h = __float22bfloat162_rn(make_float2(lo, hi));
    union { __hip_bfloat162 h; unsigned u; } v;
    v.h = h;
    return v.u;
}

// ---------------- prep: role-split — hist(dst) | pack WT2 | pack xb ----------------
// WT2[nn][k]: nn=output col (0..127), k=0..255: k<128 -> Ws[k][nn], else Wn[k-128][nn].
// xb = bf16(x), row-major n x 128.
__global__ __launch_bounds__(256) void prep_kernel(const int* __restrict__ dst,
                                                   int* __restrict__ counts, int nE,
                                                   const float* __restrict__ Ws,
                                                   const float* __restrict__ Wn,
                                                   short* __restrict__ WT2,
                                                   const float* __restrict__ x,
                                                   unsigned short* __restrict__ xb,
                                                   int nElem) {
    const int nbE = (nE + 255) >> 8;
    const int b = blockIdx.x;
    if (b < nbE) {
        int e = b * 256 + threadIdx.x;
        if (e < nE) atomicAdd(&counts[dst[e]], 1);
    } else if (b < nbE + 128) {
        int idx = (b - nbE) * 256 + threadIdx.x;  // < 128*256 = 32768
        int nn = idx >> 8;
        int k = idx & 255;
        float v = (k < D) ? Ws[k * D + nn] : Wn[(k - D) * D + nn];
        WT2[idx] = f2bf(v);
    } else {
        int idx = (b - nbE - 128) * 256 + threadIdx.x;
        int base = idx * 8;
        if (base < nElem) {
            float4 lo = *reinterpret_cast<const float4*>(x + base);
            float4 hi = *reinterpret_cast<const float4*>(x + base + 4);
            union { short8v s8; unsigned u[4]; } p;
            p.u[0] = pkbf2(lo.x, lo.y);
            p.u[1] = pkbf2(lo.z, lo.w);
            p.u[2] = pkbf2(hi.x, hi.y);
            p.u[3] = pkbf2(hi.z, hi.w);
            *reinterpret_cast<short8v*>(xb + base) = p.s8;
        }
    }
}

// ---------------- scan A: per-block (1024-chunk) totals ----------------
__global__ __launch_bounds__(256) void scan_partial_kernel(const int* __restrict__ counts,
                                                           int* __restrict__ bsums, int n) {
    __shared__ int wsum[4];
    const int t = threadIdx.x;
    const int i0 = blockIdx.x * 1024 + t * 4;
    int s = 0;
#pragma unroll
    for (int j = 0; j < 4; ++j) s += (i0 + j < n) ? counts[i0 + j] : 0;
#pragma unroll
    for (int off = 32; off > 0; off >>= 1) s += __shfl_down(s, off, 64);
    if ((t & 63) == 0) wsum[t >> 6] = s;
    __syncthreads();
    if (t == 0) bsums[blockIdx.x] = wsum[0] + wsum[1] + wsum[2] + wsum[3];
}

// ---------------- scan B: exclusive scan of block sums (nb <= 128) ----------------
__global__ __launch_bounds__(128) void scan_bsums_kernel(const int* __restrict__ bsums,
                                                         int* __restrict__ ebsums,
                                                         int* __restrict__ rowptr_n,
                                                         int nb) {
    __shared__ int sh[128];
    const int t = threadIdx.x;
    int v = (t < nb) ? bsums[t] : 0;
    sh[t] = v;
    __syncthreads();
    for (int off = 1; off < 128; off <<= 1) {
        int u = (t >= off) ? sh[t - off] : 0;
        __syncthreads();
        sh[t] += u;
        __syncthreads();
    }
    if (t < nb) ebsums[t] = sh[t] - v;  // exclusive
    if (t == 127) *rowptr_n = sh[127];  // grand total -> rowptr[n]
}

// ---------------- scan C: chunk exclusive scan + cursor init ----------------
__global__ __launch_bounds__(256) void scan_final_kernel(int* __restrict__ counts,
                                                         const int* __restrict__ ebsums,
                                                         int* __restrict__ rowptr, int n) {
    __shared__ int sh[256];
    const int t = threadIdx.x;
    const int i0 = blockIdx.x * 1024 + t * 4;
    int c[4];
    int s = 0;
#pragma unroll
    for (int j = 0; j < 4; ++j) {
        c[j] = (i0 + j < n) ? counts[i0 + j] : 0;
        s += c[j];
    }
    sh[t] = s;
    __syncthreads();
    for (int off = 1; off < 256; off <<= 1) {
        int u = (t >= off) ? sh[t - off] : 0;
        __syncthreads();
        sh[t] += u;
        __syncthreads();
    }
    int run = ebsums[blockIdx.x] + sh[t] - s;
#pragma unroll
    for (int j = 0; j < 4; ++j) {
        int i = i0 + j;
        if (i < n) {
            rowptr[i] = run;
            counts[i] = run;  // cursor init
            run += c[j];
        }
    }
}

// ---------------- CSR fill: csr[pos] = src, pos = cursor[dst]++ ----------------
__global__ __launch_bounds__(256) void fill_kernel(const int* __restrict__ src,
                                                   const int* __restrict__ dst,
                                                   int* __restrict__ cursor,
                                                   int* __restrict__ csr, int nE) {
    int e = blockIdx.x * 256 + threadIdx.x;
    if (e < nE) {
        int pos = atomicAdd(&cursor[dst[e]], 1);
        csr[pos] = src[e];
    }
}

// ---------------- gather: agg[d] (bf16x64 dwords) -> first 256B of out row d ----------
// agg[d] = mean of xb[src] over csr[d]. One wave per node, lane = 2 channels.
// Barrier-free, high occupancy. aggOut = (unsigned*)out; row stride 128 dwords.
__global__ __launch_bounds__(256) void gather_kernel(const int* __restrict__ rowptr,
                                                     const int* __restrict__ csr,
                                                     const unsigned short* __restrict__ xb,
                                                     unsigned* __restrict__ aggOut,
                                                     int n) {
    const int wave = threadIdx.x >> 6;
    const int lane = threadIdx.x & 63;
    const int d = blockIdx.x * 4 + wave;
    if (d >= n) return;  // no barriers

    const int beg = rowptr[d];
    const int end = rowptr[d + 1];
    float ax = 0.f, ay = 0.f;

    int i = beg;
    for (; i + 3 < end; i += 4) {
        int s0 = csr[i], s1 = csr[i + 1], s2 = csr[i + 2], s3 = csr[i + 3];
        unsigned v0 = *reinterpret_cast<const unsigned*>(xb + (size_t)s0 * D + lane * 2);
        unsigned v1 = *reinterpret_cast<const unsigned*>(xb + (size_t)s1 * D + lane * 2);
        unsigned v2 = *reinterpret_cast<const unsigned*>(xb + (size_t)s2 * D + lane * 2);
        unsigned v3 = *reinterpret_cast<const unsigned*>(xb + (size_t)s3 * D + lane * 2);
        ax += (bf2f(v0 & 0xffffu) + bf2f(v1 & 0xffffu)) +
              (bf2f(v2 & 0xffffu) + bf2f(v3 & 0xffffu));
        ay += (bf2f(v0 >> 16) + bf2f(v1 >> 16)) + (bf2f(v2 >> 16) + bf2f(v3 >> 16));
    }
    for (; i < end; ++i) {
        unsigned v0 = *reinterpret_cast<const unsigned*>(xb + (size_t)csr[i] * D + lane * 2);
        ax += bf2f(v0 & 0xffffu);
        ay += bf2f(v0 >> 16);
    }

    const float inv = 1.0f / fmaxf((float)(end - beg), 1.0f);
    aggOut[(size_t)d * D + lane] = pkbf2(ax * inv, ay * inv);
}

// ---------------- GEMM K=256: out = relu([xb | agg] @ WT2^T + bs + bn) ----------------
// Persistent, 4 waves/block, grid-stride over 16-row strips (n % 16 == 0).
// agg is read from the FIRST 256B of each out row (written by gather_kernel);
// __syncthreads() between A-load and store makes the in-place overwrite safe
// (blocks own disjoint strips; within a block the barrier orders read-before-write).
// B-frags (WT2) register-resident. C/D: col=lane&15, row=(lane>>4)*4+reg [m89].
__global__ __launch_bounds__(256) void gemm_kernel(const unsigned short* __restrict__ xb,
                                                   const short* __restrict__ WT2,
                                                   const float* __restrict__ bs,
                                                   const float* __restrict__ bn,
                                                   const unsigned* __restrict__ aggIn,
                                                   float* __restrict__ out,
                                                   int n, int nStrips) {
    const int wave = threadIdx.x >> 6;
    const int lane = threadIdx.x & 63;
    const int lrow = lane & 15;
    const int q = lane >> 4;
    const int ko = q * 8;

    short8v b[2][8];
#pragma unroll
    for (int j = 0; j < 2; ++j) {
        const short* __restrict__ wp = WT2 + (size_t)((wave * 2 + j) * 16 + lrow) * 256 + ko;
#pragma unroll
        for (int ks = 0; ks < 8; ++ks)
            b[j][ks] = *reinterpret_cast<const short8v*>(wp + ks * 32);
    }
    float bias[2];
#pragma unroll
    for (int j = 0; j < 2; ++j) {
        int c = (wave * 2 + j) * 16 + lrow;
        bias[j] = bs[c] + bn[c];
    }

    for (int strip = blockIdx.x; strip < nStrips; strip += gridDim.x) {
        const int m0 = strip * 16;

        // A-frags: left K=128 from xb, right K=128 from agg (in out rows)
        short8v a[8];
        const unsigned short* __restrict__ xr = xb + (size_t)(m0 + lrow) * D + ko;
        const unsigned* __restrict__ ar = aggIn + (size_t)(m0 + lrow) * D;  // dword stride 128
#pragma unroll
        for (int ks = 0; ks < 4; ++ks) {
            a[ks] = *reinterpret_cast<const short8v*>(xr + ks * 32);
            union { uint4 u4; short8v s8; } cv;
            cv.u4 = *reinterpret_cast<const uint4*>(ar + q * 4 + ks * 16);
            a[4 + ks] = cv.s8;
        }

        __syncthreads();  // all agg reads of this strip complete before any out write

        f32x4 acc[2];
        acc[0] = (f32x4){0.f, 0.f, 0.f, 0.f};
        acc[1] = (f32x4){0.f, 0.f, 0.f, 0.f};
#pragma unroll
        for (int j = 0; j < 2; ++j)
#pragma unroll
            for (int ks = 0; ks < 8; ++ks)
                acc[j] = __builtin_amdgcn_mfma_f32_16x16x32_bf16(a[ks], b[j][ks], acc[j], 0, 0, 0);

        const int r0 = m0 + q * 4;
#pragma unroll
        for (int j = 0; j < 2; ++j) {
            const int c = (wave * 2 + j) * 16 + lrow;
#pragma unroll
            for (int rg = 0; rg < 4; ++rg) {
                int r = r0 + rg;
                if (r < n) out[(size_t)r * D + c] = fmaxf(acc[j][rg] + bias[j], 0.f);
            }
        }
    }
}

extern "C" void kernel_launch(void* const* d_in, const int* in_sizes, int n_in,
                              void* d_out, int out_size, void* d_ws, size_t ws_size,
                              hipStream_t stream) {
    const float* x  = (const float*)d_in[0];
    const int*   ei = (const int*)d_in[1];
    const float* Ws = (const float*)d_in[2];
    const float* bs = (const float*)d_in[3];
    const float* Wn = (const float*)d_in[4];
    const float* bn = (const float*)d_in[5];
    float* out = (float*)d_out;

    const int n  = in_sizes[0] / D;   // 100000
    const int nE = in_sizes[1] / 2;   // 640000
    const int* src = ei;
    const int* dst = ei + nE;
    const int nb = (n + 1023) / 1024; // 98
    const int nElem = n * D;

    // workspace layout (~29.1 MB, proven budget)
    unsigned short* xb = (unsigned short*)d_ws;           // n*D bf16 (25.6 MB)
    short* WT2   = (short*)(xb + (size_t)nElem);          // 128*256 bf16 (64 KB)
    int*   counts = (int*)(WT2 + (size_t)D * 256);        // n int (becomes cursor)
    int*   rowptr = counts + n;                           // n+1 int
    int*   csr    = rowptr + n + 1;                       // nE int (2.56 MB)
    int*   bsums  = csr + nE;                             // 128 int
    int*   ebsums = bsums + 128;                          // 128 int

    const int nbE = (nE + 255) / 256;              // 2500
    const int nXb = (nElem / 8 + 255) / 256;       // 6250

    hipMemsetAsync(counts, 0, (size_t)n * sizeof(int), stream);
    prep_kernel<<<nbE + 128 + nXb, 256, 0, stream>>>(dst, counts, nE, Ws, Wn, WT2, x, xb, nElem);
    scan_partial_kernel<<<nb, 256, 0, stream>>>(counts, bsums, n);
    scan_bsums_kernel<<<1, 128, 0, stream>>>(bsums, ebsums, rowptr + n, nb);
    scan_final_kernel<<<nb, 256, 0, stream>>>(counts, ebsums, rowptr, n);
    fill_kernel<<<(nE + 255) / 256, 256, 0, stream>>>(src, dst, counts, csr, nE);

    gather_kernel<<<(n + 3) / 4, 256, 0, stream>>>(rowptr, csr, xb, (unsigned*)out, n);

    const int nStrips = (n + 15) / 16;  // 6250
    const int gGrid = nStrips < 2048 ? nStrips : 2048;
    gemm_kernel<<<gGrid, 256, 0, stream>>>(xb, WT2, bs, bn, (const unsigned*)out, out, n, nStrips);
}

// Round 10
// 165.605 us; speedup vs baseline: 1.0821x; 1.0298x over previous
//
#include <hip/hip_runtime.h>
#include <hip/hip_bf16.h>

#define D 128

typedef __attribute__((ext_vector_type(8))) short short8v;  // 8 bf16 (4 VGPRs)
typedef __attribute__((ext_vector_type(4))) float f32x4;

__device__ __forceinline__ short f2bf(float f) {
    union { float f; unsigned u; } v;
    v.f = f;
    unsigned u = v.u;
    unsigned r = (u + 0x7FFFu + ((u >> 16) & 1u)) >> 16;  // RNE
    return (short)r;
}

__device__ __forceinline__ float bf2f(unsigned u16) {
    union { unsigned u; float f; } v;
    v.u = u16 << 16;
    return v.f;
}

// pack two f32 -> one dword of 2 bf16 (v_cvt_pk_bf16_f32)
__device__ __forceinline__ unsigned pkbf2(float lo, float hi) {
    __hip_bfloat162 h = __float22bfloat162_rn(make_float2(lo, hi));
    union { __hip_bfloat162 h; unsigned u; } v;
    v.h = h;
    return v.u;
}

// ---------------- prep: role-split — hist(dst) | pack WT2 | pack xb ----------------
// WT2[nn][k]: nn=output col (0..127), k=0..255: k<128 -> Ws[k][nn], else Wn[k-128][nn].
// xb = bf16(x), row-major n x 128.
__global__ __launch_bounds__(256) void prep_kernel(const int* __restrict__ dst,
                                                   int* __restrict__ counts, int nE,
                                                   const float* __restrict__ Ws,
                                                   const float* __restrict__ Wn,
                                                   short* __restrict__ WT2,
                                                   const float* __restrict__ x,
                                                   unsigned short* __restrict__ xb,
                                                   int nElem) {
    const int nbE = (nE + 255) >> 8;
    const int b = blockIdx.x;
    if (b < nbE) {
        int e = b * 256 + threadIdx.x;
        if (e < nE) atomicAdd(&counts[dst[e]], 1);
    } else if (b < nbE + 128) {
        int idx = (b - nbE) * 256 + threadIdx.x;  // < 128*256 = 32768
        int nn = idx >> 8;
        int k = idx & 255;
        float v = (k < D) ? Ws[k * D + nn] : Wn[(k - D) * D + nn];
        WT2[idx] = f2bf(v);
    } else {
        int idx = (b - nbE - 128) * 256 + threadIdx.x;
        int base = idx * 8;
        if (base < nElem) {
            float4 lo = *reinterpret_cast<const float4*>(x + base);
            float4 hi = *reinterpret_cast<const float4*>(x + base + 4);
            union { short8v s8; unsigned u[4]; } p;
            p.u[0] = pkbf2(lo.x, lo.y);
            p.u[1] = pkbf2(lo.z, lo.w);
            p.u[2] = pkbf2(hi.x, hi.y);
            p.u[3] = pkbf2(hi.z, hi.w);
            *reinterpret_cast<short8v*>(xb + base) = p.s8;
        }
    }
}

// ---------------- single-kernel scan: counts -> rowptr + cursor init ----------------
// nb (=98) blocks are all co-resident (<< 256 CUs) so a done-counter spin is
// deadlock-free. bsums reads use atomic loads (per-XCD L2 non-coherence, G16).
__global__ __launch_bounds__(256) void scan_fused_kernel(int* __restrict__ counts,
                                                         int* __restrict__ bsums,
                                                         int* __restrict__ done,
                                                         int* __restrict__ rowptr,
                                                         int n, int nb) {
    __shared__ int sh[256];
    __shared__ int s_base, s_total;
    const int b = blockIdx.x;
    const int t = threadIdx.x;
    const int i0 = b * 1024 + t * 4;
    int c[4];
    int s = 0;
#pragma unroll
    for (int j = 0; j < 4; ++j) {
        c[j] = (i0 + j < n) ? counts[i0 + j] : 0;
        s += c[j];
    }
    sh[t] = s;
    __syncthreads();
    // Hillis-Steele inclusive scan over 256 thread-sums
    for (int off = 1; off < 256; off <<= 1) {
        int u = (t >= off) ? sh[t - off] : 0;
        __syncthreads();
        sh[t] += u;
        __syncthreads();
    }
    const int blockAgg = sh[255];
    if (t == 0) {
        bsums[b] = blockAgg;
        __threadfence();            // publish before counting
        atomicAdd(done, 1);
        while (atomicAdd(done, 0) < nb) { }  // spin (all blocks resident)
    }
    __syncthreads();
    // every thread: contribution to (prefix of blocks < b) and (grand total)
    int xv = (t < nb) ? atomicAdd(&bsums[t], 0) : 0;  // atomic load, cross-XCD safe
    int vb = (t < b) ? xv : 0;
#pragma unroll
    for (int off = 32; off > 0; off >>= 1) {
        vb += __shfl_down(vb, off, 64);
        xv += __shfl_down(xv, off, 64);
    }
    if (t == 0) { s_base = vb; s_total = xv; }          // wave 0 holds t<64
    else if (t == 64 && nb > 64) { atomicAdd(&s_base, 0); }  // placeholder no-op
    __syncthreads();
    if (t == 64) {  // wave 1 adds its partial (nb<=128 so waves 2,3 contribute 0)
        atomicAdd(&s_base, vb);
        atomicAdd(&s_total, xv);
    }
    __syncthreads();
    const int base = s_base;
    int run = base + sh[t] - s;  // exclusive prefix for this thread's 4 elems
#pragma unroll
    for (int j = 0; j < 4; ++j) {
        int i = i0 + j;
        if (i < n) {
            rowptr[i] = run;
            counts[i] = run;  // cursor init
            run += c[j];
        }
    }
    if (b == nb - 1 && t == 0) rowptr[n] = s_total;
}

// ---------------- CSR fill: csr[pos] = src, pos = cursor[dst]++ ----------------
__global__ __launch_bounds__(256) void fill_kernel(const int* __restrict__ src,
                                                   const int* __restrict__ dst,
                                                   int* __restrict__ cursor,
                                                   int* __restrict__ csr, int nE) {
    int e = blockIdx.x * 256 + threadIdx.x;
    if (e < nE) {
        int pos = atomicAdd(&cursor[dst[e]], 1);
        csr[pos] = src[e];
    }
}

// ---------------- gather: agg[d] (bf16x64 dwords) -> first 256B of out row d ----------
// Two nodes per wave (independent chains -> 4 loads in flight; branches wave-uniform).
__global__ __launch_bounds__(256) void gather_kernel(const int* __restrict__ rowptr,
                                                     const int* __restrict__ csr,
                                                     const unsigned short* __restrict__ xb,
                                                     unsigned* __restrict__ aggOut,
                                                     int n) {
    const int wave = threadIdx.x >> 6;
    const int lane = threadIdx.x & 63;
    const int d0 = blockIdx.x * 8 + wave * 2;
    if (d0 >= n) return;  // no barriers
    const bool has1 = (d0 + 1) < n;

    int iA = rowptr[d0];
    const int endA = rowptr[d0 + 1];
    int iB = has1 ? endA : 0;
    const int endB = has1 ? rowptr[d0 + 2] : 0;
    const int ofs = lane * 2;

    float ax0 = 0.f, ay0 = 0.f, ax1 = 0.f, ay1 = 0.f;

    while (iA + 2 <= endA && iB + 2 <= endB) {
        int a0 = csr[iA], a1 = csr[iA + 1], b0 = csr[iB], b1 = csr[iB + 1];
        unsigned v0 = *reinterpret_cast<const unsigned*>(xb + (size_t)a0 * D + ofs);
        unsigned v1 = *reinterpret_cast<const unsigned*>(xb + (size_t)a1 * D + ofs);
        unsigned w0 = *reinterpret_cast<const unsigned*>(xb + (size_t)b0 * D + ofs);
        unsigned w1 = *reinterpret_cast<const unsigned*>(xb + (size_t)b1 * D + ofs);
        ax0 += bf2f(v0 & 0xffffu) + bf2f(v1 & 0xffffu);
        ay0 += bf2f(v0 >> 16) + bf2f(v1 >> 16);
        ax1 += bf2f(w0 & 0xffffu) + bf2f(w1 & 0xffffu);
        ay1 += bf2f(w0 >> 16) + bf2f(w1 >> 16);
        iA += 2;
        iB += 2;
    }
    while (iA + 2 <= endA) {
        int a0 = csr[iA], a1 = csr[iA + 1];
        unsigned v0 = *reinterpret_cast<const unsigned*>(xb + (size_t)a0 * D + ofs);
        unsigned v1 = *reinterpret_cast<const unsigned*>(xb + (size_t)a1 * D + ofs);
        ax0 += bf2f(v0 & 0xffffu) + bf2f(v1 & 0xffffu);
        ay0 += bf2f(v0 >> 16) + bf2f(v1 >> 16);
        iA += 2;
    }
    while (iB + 2 <= endB) {
        int b0 = csr[iB], b1 = csr[iB + 1];
        unsigned w0 = *reinterpret_cast<const unsigned*>(xb + (size_t)b0 * D + ofs);
        unsigned w1 = *reinterpret_cast<const unsigned*>(xb + (size_t)b1 * D + ofs);
        ax1 += bf2f(w0 & 0xffffu) + bf2f(w1 & 0xffffu);
        ay1 += bf2f(w0 >> 16) + bf2f(w1 >> 16);
        iB += 2;
    }
    if (iA < endA) {
        unsigned v0 = *reinterpret_cast<const unsigned*>(xb + (size_t)csr[iA] * D + ofs);
        ax0 += bf2f(v0 & 0xffffu);
        ay0 += bf2f(v0 >> 16);
    }
    if (iB < endB) {
        unsigned w0 = *reinterpret_cast<const unsigned*>(xb + (size_t)csr[iB] * D + ofs);
        ax1 += bf2f(w0 & 0xffffu);
        ay1 += bf2f(w0 >> 16);
    }

    const int degA = endA - iA + (iA - rowptr[d0]);  // == endA - rowptr[d0]
    const float invA = 1.0f / fmaxf((float)(endA - rowptr[d0]), 1.0f);
    aggOut[(size_t)d0 * D + lane] = pkbf2(ax0 * invA, ay0 * invA);
    (void)degA;
    if (has1) {
        const float invB = 1.0f / fmaxf((float)(endB - endA), 1.0f);
        aggOut[(size_t)(d0 + 1) * D + lane] = pkbf2(ax1 * invB, ay1 * invB);
    }
}

// ---------------- GEMM K=256: out = relu([xb | agg] @ WT2^T + bs + bn) ----------------
// SWAPPED operands: D' = mfma(W_frag, x_frag) = (x@W)^T fragment-wise, so each lane
// holds 4 CONSECUTIVE channels (q*4+rg) of out-row (m0+lrow) -> float4 stores.
// agg read from first 256B of out rows (written by gather); barrier between A-load
// and store orders the in-place overwrite (blocks own disjoint strips).
__global__ __launch_bounds__(256) void gemm_kernel(const unsigned short* __restrict__ xb,
                                                   const short* __restrict__ WT2,
                                                   const float* __restrict__ bs,
                                                   const float* __restrict__ bn,
                                                   const unsigned* __restrict__ aggIn,
                                                   float* __restrict__ out,
                                                   int n, int nStrips) {
    const int wave = threadIdx.x >> 6;
    const int lane = threadIdx.x & 63;
    const int lrow = lane & 15;
    const int q = lane >> 4;
    const int ko = q * 8;

    short8v b[2][8];
#pragma unroll
    for (int j = 0; j < 2; ++j) {
        const short* __restrict__ wp = WT2 + (size_t)((wave * 2 + j) * 16 + lrow) * 256 + ko;
#pragma unroll
        for (int ks = 0; ks < 8; ++ks)
            b[j][ks] = *reinterpret_cast<const short8v*>(wp + ks * 32);
    }
    float4 bias[2];
#pragma unroll
    for (int j = 0; j < 2; ++j) {
        const int cb = (wave * 2 + j) * 16 + q * 4;
        float4 v1 = *reinterpret_cast<const float4*>(bs + cb);
        float4 v2 = *reinterpret_cast<const float4*>(bn + cb);
        bias[j] = make_float4(v1.x + v2.x, v1.y + v2.y, v1.z + v2.z, v1.w + v2.w);
    }

    for (int strip = blockIdx.x; strip < nStrips; strip += gridDim.x) {
        const int m0 = strip * 16;

        // A-frags (x side as B-operand): left K=128 xb, right K=128 agg (in out rows)
        short8v a[8];
        const unsigned short* __restrict__ xr = xb + (size_t)(m0 + lrow) * D + ko;
        const unsigned* __restrict__ ar = aggIn + (size_t)(m0 + lrow) * D;  // dword stride 128
#pragma unroll
        for (int ks = 0; ks < 4; ++ks) {
            a[ks] = *reinterpret_cast<const short8v*>(xr + ks * 32);
            union { uint4 u4; short8v s8; } cv;
            cv.u4 = *reinterpret_cast<const uint4*>(ar + q * 4 + ks * 16);
            a[4 + ks] = cv.s8;
        }

        __syncthreads();  // all agg reads of this strip complete before any out write

        f32x4 acc[2];
        acc[0] = (f32x4){0.f, 0.f, 0.f, 0.f};
        acc[1] = (f32x4){0.f, 0.f, 0.f, 0.f};
#pragma unroll
        for (int j = 0; j < 2; ++j)
#pragma unroll
            for (int ks = 0; ks < 8; ++ks)
                acc[j] = __builtin_amdgcn_mfma_f32_16x16x32_bf16(b[j][ks], a[ks], acc[j], 0, 0, 0);

        // epilogue: row = m0+lrow, channels cb..cb+3 contiguous -> float4
        const size_t rb = (size_t)(m0 + lrow) * D;
#pragma unroll
        for (int j = 0; j < 2; ++j) {
            const int cb = (wave * 2 + j) * 16 + q * 4;
            float4 o;
            o.x = fmaxf(acc[j][0] + bias[j].x, 0.f);
            o.y = fmaxf(acc[j][1] + bias[j].y, 0.f);
            o.z = fmaxf(acc[j][2] + bias[j].z, 0.f);
            o.w = fmaxf(acc[j][3] + bias[j].w, 0.f);
            *reinterpret_cast<float4*>(out + rb + cb) = o;
        }
    }
}

extern "C" void kernel_launch(void* const* d_in, const int* in_sizes, int n_in,
                              void* d_out, int out_size, void* d_ws, size_t ws_size,
                              hipStream_t stream) {
    const float* x  = (const float*)d_in[0];
    const int*   ei = (const int*)d_in[1];
    const float* Ws = (const float*)d_in[2];
    const float* bs = (const float*)d_in[3];
    const float* Wn = (const float*)d_in[4];
    const float* bn = (const float*)d_in[5];
    float* out = (float*)d_out;

    const int n  = in_sizes[0] / D;   // 100000
    const int nE = in_sizes[1] / 2;   // 640000
    const int* src = ei;
    const int* dst = ei + nE;
    const int nb = (n + 1023) / 1024; // 98 (must be <= 128 and co-resident)
    const int nElem = n * D;

    // workspace layout (~29.1 MB)
    unsigned short* xb = (unsigned short*)d_ws;           // n*D bf16 (25.6 MB)
    short* WT2   = (short*)(xb + (size_t)nElem);          // 128*256 bf16 (64 KB)
    int*   counts = (int*)(WT2 + (size_t)D * 256);        // n int (becomes cursor)
    int*   bsums  = counts + n;                           // 128 int
    int*   done   = bsums + 128;                          // 1 int
    int*   rowptr = done + 1;                             // n+1 int
    int*   csr    = rowptr + n + 1;                       // nE int (2.56 MB)

    const int nbE = (nE + 255) / 256;              // 2500
    const int nXb = (nElem / 8 + 255) / 256;       // 6250

    hipMemsetAsync(counts, 0, (size_t)(n + 129) * sizeof(int), stream);
    prep_kernel<<<nbE + 128 + nXb, 256, 0, stream>>>(dst, counts, nE, Ws, Wn, WT2, x, xb, nElem);
    scan_fused_kernel<<<nb, 256, 0, stream>>>(counts, bsums, done, rowptr, n, nb);
    fill_kernel<<<(nE + 255) / 256, 256, 0, stream>>>(src, dst, counts, csr, nE);

    gather_kernel<<<(n + 7) / 8, 256, 0, stream>>>(rowptr, csr, xb, (unsigned*)out, n);

    const int nStrips = (n + 15) / 16;  // 6250
    const int gGrid = nStrips < 2048 ? nStrips : 2048;
    gemm_kernel<<<gGrid, 256, 0, stream>>>(xb, WT2, bs, bn, (const unsigned*)out, out, n, nStrips);
}